// Round 6
// baseline (22.711 us; speedup 1.0000x reference)
//
#include <hip/hip_runtime.h>

#define FEAT 128
#define HID 32
#define NPB 64           // nodes (M rows) per block; 4 waves x 16 rows
#define BLOCK 256

typedef __attribute__((ext_vector_type(8))) __bf16 bf16x8;
typedef __attribute__((ext_vector_type(8))) unsigned short ushortx8;
typedef __attribute__((ext_vector_type(4))) float floatx4;

static __device__ inline unsigned short f2u(float f) {
    return __builtin_bit_cast(unsigned short, (__bf16)f);   // RTNE, pairs fuse to v_cvt_pk_bf16_f32
}
static __device__ inline float fsig(float v) {
    return __builtin_amdgcn_rcpf(1.f + __expf(-v));
}
static __device__ inline float ftanh(float v) {
    return 1.f - 2.f * __builtin_amdgcn_rcpf(__expf(2.f * v) + 1.f);
}

// ---- prep: combined bf16 weights in EXACT B-fragment order (validated in R3) ----
// main reads fragment f=(s*4+nt): lane l, elem j  <-  wfrag[(f*64+l)*8 + j]
// value = Wc[k = s*32 + (l>>4)*8 + j][o = nt*16 + (l&15)],
// Wc[k][o] = Wgate[0,0,k,o&31] + Wgate[1,0,k,o&31], gate = z if o<32 else h.
__global__ void prep_wfrag(const float* __restrict__ Wz,
                           const float* __restrict__ Wh,
                           unsigned short* __restrict__ wfrag) {
    int e = blockIdx.x * blockDim.x + threadIdx.x;   // 0..8191
    if (e >= 16 * 64 * 8) return;
    int j = e & 7, l = (e >> 3) & 63, f = e >> 9;
    int nt = f & 3, s = f >> 2;
    int k = s * 32 + (l >> 4) * 8 + j;
    int o = nt * 16 + (l & 15);
    const float* W = (o < HID) ? Wz : Wh;
    int col = o & 31;
    // W shape (2,1,160,32): [d,0,k,col] at d*5120 + k*32 + col (k<128: x-part)
    float v = W[k * HID + col] + W[5120 + k * HID + col];
    wfrag[e] = f2u(v);
}

// ---- main: B fragments in REGISTERS (one coalesced load each), X via LDS ----
__global__ __launch_bounds__(BLOCK, 3) void dcrnn_main(
    const float* __restrict__ x,
    const unsigned short* __restrict__ wfrag,
    const float* __restrict__ bz, const float* __restrict__ bh,
    const float* __restrict__ wl, const float* __restrict__ bl,
    float* __restrict__ out, int n_nodes)
{
    __shared__ unsigned short sX[NPB * FEAT];    // 16 KB bf16, XOR-swizzled rows

    const int tid = threadIdx.x;
    const int l  = tid & 63;
    const long long node0 = (long long)blockIdx.x * NPB;

    // ---- issue X global loads (HBM) ----
    float4 xa[4], xb[4];
    #pragma unroll
    for (int p = 0; p < 4; ++p) {
        const int idx8 = p * BLOCK + tid;        // 0..1023: row=idx8>>4, k0=(idx8&15)*8
        const int row = idx8 >> 4, k0 = (idx8 & 15) * 8;
        const long long node = node0 + row;
        if (node < n_nodes) {
            xa[p] = *(const float4*)&x[node * FEAT + k0];
            xb[p] = *(const float4*)&x[node * FEAT + k0 + 4];
        } else {
            xa[p] = make_float4(0.f, 0.f, 0.f, 0.f);
            xb[p] = make_float4(0.f, 0.f, 0.f, 0.f);
        }
    }

    // ---- B fragments -> registers (L2-hot 16 KB, coalesced 1 KB/instr) ----
    ushortx8 bfr[16];
    #pragma unroll
    for (int f = 0; f < 16; ++f)
        bfr[f] = *(const ushortx8*)(wfrag + (f * 64 + l) * 8);

    // ---- epilogue constants (issue early, L1-hot) ----
    const int n0 = l & 15;       // A row within tile / B col / C col
    const int g  = l >> 4;       // k-group / C row-group
    const float bz0 = bz[n0], bz1 = bz[n0 + 16];
    const float bh0 = bh[n0], bh1 = bh[n0 + 16];
    const float wl0 = wl[n0], wl1 = wl[n0 + 16];
    const float blv = bl[0];

    // ---- convert + write X tile (b128, swizzled rows) ----
    #pragma unroll
    for (int p = 0; p < 4; ++p) {
        const int idx8 = p * BLOCK + tid;
        const int row = idx8 >> 4, k0 = (idx8 & 15) * 8;
        ushortx8 v;
        v[0] = f2u(xa[p].x); v[1] = f2u(xa[p].y); v[2] = f2u(xa[p].z); v[3] = f2u(xa[p].w);
        v[4] = f2u(xb[p].x); v[5] = f2u(xb[p].y); v[6] = f2u(xb[p].z); v[7] = f2u(xb[p].w);
        *(ushortx8*)&sX[row * FEAT + (k0 ^ ((row & 7) << 3))] = v;
    }
    __syncthreads();

    // ---- MFMA: wave w owns M-rows [w*16, w*16+16); 4 N-tiles x 4 K-steps ----
    const int w = tid >> 6;

    floatx4 acc[4] = {{0,0,0,0},{0,0,0,0},{0,0,0,0},{0,0,0,0}};

    #pragma unroll
    for (int s = 0; s < 4; ++s) {
        const int k0 = s * 32 + g * 8;
        const int ar = w * 16 + n0;
        bf16x8 afrag = __builtin_bit_cast(bf16x8,
            *(const ushortx8*)&sX[ar * FEAT + (k0 ^ ((ar & 7) << 3))]);
        #pragma unroll
        for (int nt = 0; nt < 4; ++nt)
            acc[nt] = __builtin_amdgcn_mfma_f32_16x16x32_bf16(
                afrag, __builtin_bit_cast(bf16x8, bfr[s * 4 + nt]), acc[nt], 0, 0, 0);
    }

    // ---- epilogue: gates + relu + W_lin dot (16-lane reduce), float4 store ----
    float4 res;
    float* resp = &res.x;
    #pragma unroll
    for (int r = 0; r < 4; ++r) {
        float z0 = fsig(acc[0][r] + bz0);
        float z1 = fsig(acc[1][r] + bz1);
        float h0 = ftanh(acc[2][r] + bh0);
        float h1 = ftanh(acc[3][r] + bh1);
        float v0 = (1.f - z0) * h0; v0 = v0 > 0.f ? v0 : 0.f;
        float v1 = (1.f - z1) * h1; v1 = v1 > 0.f ? v1 : 0.f;
        float s = v0 * wl0 + v1 * wl1;
        s += __shfl_xor(s, 1);
        s += __shfl_xor(s, 2);
        s += __shfl_xor(s, 4);
        s += __shfl_xor(s, 8);
        resp[r] = s + blv;
    }
    if (n0 == 0) {
        long long m = node0 + w * 16 + g * 4;    // m%4==0, n_nodes%4==0
        if (m < n_nodes) *(float4*)&out[m] = res;
    }
}

extern "C" void kernel_launch(void* const* d_in, const int* in_sizes, int n_in,
                              void* d_out, int out_size, void* d_ws, size_t ws_size,
                              hipStream_t stream) {
    // inputs: 0:x 1:edge_index(dead) 2:edge_weight(dead) 3:W_z 4:b_z 5:W_r(dead)
    //         6:b_r(dead) 7:W_h 8:b_h 9:W_lin 10:b_lin
    const float* x    = (const float*)d_in[0];
    const float* Wz   = (const float*)d_in[3];
    const float* bz   = (const float*)d_in[4];
    const float* Wh   = (const float*)d_in[7];
    const float* bh   = (const float*)d_in[8];
    const float* Wlin = (const float*)d_in[9];
    const float* blin = (const float*)d_in[10];
    float* out = (float*)d_out;

    unsigned short* wfrag = (unsigned short*)d_ws;   // 16*64*8 bf16 = 16 KB

    const int n_nodes = in_sizes[0] / FEAT;

    prep_wfrag<<<(16 * 64 * 8 + BLOCK - 1) / BLOCK, BLOCK, 0, stream>>>(Wz, Wh, wfrag);

    const int grid = (n_nodes + NPB - 1) / NPB;
    dcrnn_main<<<grid, BLOCK, 0, stream>>>(x, wfrag, bz, bh, Wlin, blin, out, n_nodes);
}

// Round 7
// 19.052 us; speedup vs baseline: 1.1921x; 1.1921x over previous
//
#include <hip/hip_runtime.h>

#define FEAT 128
#define HID 32
#define NPB 128          // nodes (M rows) per block; 8 waves x 16 rows
#define BLOCK 512

typedef __attribute__((ext_vector_type(8))) __bf16 bf16x8;
typedef __attribute__((ext_vector_type(8))) unsigned short ushortx8;
typedef __attribute__((ext_vector_type(4))) float floatx4;

static __device__ inline unsigned short f2u(float f) {
    return __builtin_bit_cast(unsigned short, (__bf16)f);   // RTNE, pairs fuse to v_cvt_pk_bf16_f32
}
static __device__ inline float fsig(float v) {
    return __builtin_amdgcn_rcpf(1.f + __expf(-v));
}
static __device__ inline float ftanh(float v) {
    return 1.f - 2.f * __builtin_amdgcn_rcpf(__expf(2.f * v) + 1.f);
}

// Single fused kernel, NPB=128 / 8 waves:
//  - X tile (128x128 fp32 -> bf16) staged to LDS, XOR-swizzled rows.
//  - W combined (W[0,0]+W[1,0], gates z|h) staged to LDS in FRAGMENT-LINEAR order:
//    sWf[((s*4+nt)*64 + lane)*8 + j] == Wc[k = s*32+(lane>>4)*8+j][o = nt*16+(lane&15)]
//    (contiguous ds_write_b128 / lane-consecutive ds_read_b128, zero conflicts).
__global__ __launch_bounds__(BLOCK, 6) void dcrnn_one(
    const float* __restrict__ x,
    const float* __restrict__ Wz, const float* __restrict__ Wh,
    const float* __restrict__ bz, const float* __restrict__ bh,
    const float* __restrict__ wl, const float* __restrict__ bl,
    float* __restrict__ out, int n_nodes)
{
    __shared__ unsigned short sX[NPB * FEAT];    // 32 KB
    __shared__ unsigned short sWf[16 * 64 * 8];  // 16 KB, fragment-linear
    // 48 KB total -> 3 blocks/CU (24 waves/CU)

    const int tid = threadIdx.x;
    const long long node0 = (long long)blockIdx.x * NPB;

    // ---- (a) issue X global loads first (HBM latency hides under W staging) ----
    float4 xa[4], xb[4];
    #pragma unroll
    for (int p = 0; p < 4; ++p) {
        const int idx8 = p * BLOCK + tid;        // 0..2047: row=idx8>>4 (0..127), k0=(idx8&15)*8
        const int row = idx8 >> 4, k0 = (idx8 & 15) * 8;
        const long long node = node0 + row;
        if (node < n_nodes) {
            xa[p] = *(const float4*)&x[node * FEAT + k0];
            xb[p] = *(const float4*)&x[node * FEAT + k0 + 4];
        } else {
            xa[p] = make_float4(0.f, 0.f, 0.f, 0.f);
            xb[p] = make_float4(0.f, 0.f, 0.f, 0.f);
        }
    }

    // ---- (b) combine + stage W fragments (L2-hot reads, b128 LDS writes) ----
    // W shape (2,1,160,32): [d,0,k,col] at d*5120 + k*32 + col; k<128 is the x-part.
    #pragma unroll
    for (int p = 0; p < 2; ++p) {
        const int e8 = p * BLOCK + tid;          // ushortx8 index, 0..1023
        const int f = e8 >> 6, l = e8 & 63;
        const int nt = f & 3, s = f >> 2;
        const int kbase = s * 32 + (l >> 4) * 8;
        const int o = nt * 16 + (l & 15);
        const float* __restrict__ W = (o < HID) ? Wz : Wh;  // wave-uniform (f fixed per wave)
        const int col = o & 31;
        ushortx8 v;
        #pragma unroll
        for (int j = 0; j < 8; ++j) {
            const int a = (kbase + j) * HID + col;
            v[j] = f2u(W[a] + W[5120 + a]);
        }
        *(ushortx8*)&sWf[e8 * 8] = v;
    }

    // ---- (c) convert + write X tile (b128, swizzled rows) ----
    #pragma unroll
    for (int p = 0; p < 4; ++p) {
        const int idx8 = p * BLOCK + tid;
        const int row = idx8 >> 4, k0 = (idx8 & 15) * 8;
        ushortx8 v;
        v[0] = f2u(xa[p].x); v[1] = f2u(xa[p].y); v[2] = f2u(xa[p].z); v[3] = f2u(xa[p].w);
        v[4] = f2u(xb[p].x); v[5] = f2u(xb[p].y); v[6] = f2u(xb[p].z); v[7] = f2u(xb[p].w);
        *(ushortx8*)&sX[row * FEAT + (k0 ^ ((row & 7) << 3))] = v;
    }
    __syncthreads();

    // ---- (d) MFMA: wave w owns M-rows [w*16, w*16+16); 4 N-tiles x 4 K-steps ----
    const int w  = tid >> 6;     // 0..7
    const int l  = tid & 63;
    const int n0 = l & 15;       // A row within tile / B col / C col
    const int g  = l >> 4;       // k-group / C row-group

    floatx4 acc[4] = {{0,0,0,0},{0,0,0,0},{0,0,0,0},{0,0,0,0}};

    #pragma unroll
    for (int s = 0; s < 4; ++s) {
        const int k0 = s * 32 + g * 8;
        const int ar = w * 16 + n0;
        bf16x8 afrag = __builtin_bit_cast(bf16x8,
            *(const ushortx8*)&sX[ar * FEAT + (k0 ^ ((ar & 7) << 3))]);
        #pragma unroll
        for (int nt = 0; nt < 4; ++nt) {
            bf16x8 bfrag = __builtin_bit_cast(bf16x8,
                *(const ushortx8*)&sWf[((s * 4 + nt) * 64 + l) * 8]);
            acc[nt] = __builtin_amdgcn_mfma_f32_16x16x32_bf16(afrag, bfrag, acc[nt], 0, 0, 0);
        }
    }

    // ---- (e) epilogue: gates + relu + W_lin dot (16-lane reduce), float4 store ----
    const float bz0 = bz[n0], bz1 = bz[n0 + 16];
    const float bh0 = bh[n0], bh1 = bh[n0 + 16];
    const float wl0 = wl[n0], wl1 = wl[n0 + 16];
    const float blv = bl[0];

    float4 res;
    float* resp = &res.x;
    #pragma unroll
    for (int r = 0; r < 4; ++r) {
        float z0 = fsig(acc[0][r] + bz0);
        float z1 = fsig(acc[1][r] + bz1);
        float h0 = ftanh(acc[2][r] + bh0);
        float h1 = ftanh(acc[3][r] + bh1);
        float v0 = (1.f - z0) * h0; v0 = v0 > 0.f ? v0 : 0.f;
        float v1 = (1.f - z1) * h1; v1 = v1 > 0.f ? v1 : 0.f;
        float s = v0 * wl0 + v1 * wl1;
        s += __shfl_xor(s, 1);
        s += __shfl_xor(s, 2);
        s += __shfl_xor(s, 4);
        s += __shfl_xor(s, 8);
        resp[r] = s + blv;
    }
    if (n0 == 0) {
        long long m = node0 + w * 16 + g * 4;    // m%4==0, n_nodes%4==0
        if (m < n_nodes) *(float4*)&out[m] = res;
    }
}

extern "C" void kernel_launch(void* const* d_in, const int* in_sizes, int n_in,
                              void* d_out, int out_size, void* d_ws, size_t ws_size,
                              hipStream_t stream) {
    // inputs: 0:x 1:edge_index(dead) 2:edge_weight(dead) 3:W_z 4:b_z 5:W_r(dead)
    //         6:b_r(dead) 7:W_h 8:b_h 9:W_lin 10:b_lin
    const float* x    = (const float*)d_in[0];
    const float* Wz   = (const float*)d_in[3];
    const float* bz   = (const float*)d_in[4];
    const float* Wh   = (const float*)d_in[7];
    const float* bh   = (const float*)d_in[8];
    const float* Wlin = (const float*)d_in[9];
    const float* blin = (const float*)d_in[10];
    float* out = (float*)d_out;

    const int n_nodes = in_sizes[0] / FEAT;
    const int grid = (n_nodes + NPB - 1) / NPB;
    dcrnn_one<<<grid, BLOCK, 0, stream>>>(x, Wz, Wh, bz, bh, Wlin, blin, out, n_nodes);
}

// Round 8
// 18.839 us; speedup vs baseline: 1.2056x; 1.0113x over previous
//
#include <hip/hip_runtime.h>

#define FEAT 128
#define HID 32
#define BLOCK 256        // 4 waves; ONE 16-row strip per wave
#define NSTRIPS 6250     // 100000 / 16 exactly

typedef __attribute__((ext_vector_type(8))) __bf16 bf16x8;
typedef __attribute__((ext_vector_type(8))) unsigned short ushortx8;
typedef __attribute__((ext_vector_type(4))) float floatx4;

static __device__ inline unsigned short f2u(float f) {
    return __builtin_bit_cast(unsigned short, (__bf16)f);   // RTNE, pairs fuse to v_cvt_pk_bf16_f32
}
static __device__ inline float fsig(float v) {
    return __builtin_amdgcn_rcpf(1.f + __expf(-v));
}
static __device__ inline float ftanh(float v) {
    return 1.f - 2.f * __builtin_amdgcn_rcpf(__expf(2.f * v) + 1.f);
}

// Wave-autonomous: one 16-row strip per wave (6250 strips, perfectly balanced).
// W combined to LDS in fragment-linear order (one barrier); A-fragments loaded
// DIRECTLY from global (R3-validated layout); no X-LDS, no further syncs.
__global__ __launch_bounds__(BLOCK, 5) void dcrnn_wave(
    const float* __restrict__ x,
    const float* __restrict__ Wz, const float* __restrict__ Wh,
    const float* __restrict__ bz, const float* __restrict__ bh,
    const float* __restrict__ wl, const float* __restrict__ bl,
    float* __restrict__ out, int n_nodes)
{
    __shared__ unsigned short sWf[16 * 64 * 8];   // 16 KB, fragment-linear

    const int tid = threadIdx.x;
    const int wid = tid >> 6;
    const int l   = tid & 63;
    const int n0  = l & 15;      // A row within strip / B col / C col
    const int g   = l >> 4;      // k-group / C row-group

    const int strip = blockIdx.x * 4 + wid;
    const bool active = strip < NSTRIPS;

    // ---- (a) issue this wave's A loads immediately (HBM latency starts now) ----
    const long long row = (long long)(active ? strip : 0) * 16 + n0;
    const float* xr = x + row * FEAT + g * 8;
    float4 xa[4], xb[4];
    #pragma unroll
    for (int s = 0; s < 4; ++s) {
        xa[s] = *(const float4*)(xr + s * 32);
        xb[s] = *(const float4*)(xr + s * 32 + 4);
    }

    // ---- (b) cooperative W combine + stage (overlaps the HBM wait) ----
    // W shape (2,1,160,32): [d,0,k,col] at d*5120 + k*32 + col; k<128 is the x-part.
    // sWf[((s*4+nt)*64 + lane)*8 + j] == Wc[k = s*32+(lane>>4)*8+j][o = nt*16+(lane&15)]
    #pragma unroll
    for (int p = 0; p < 4; ++p) {
        const int e8 = p * BLOCK + tid;           // ushortx8 index, 0..1023
        const int f = e8 >> 6, wl_ = e8 & 63;
        const int nt = f & 3, s = f >> 2;
        const int kbase = s * 32 + (wl_ >> 4) * 8;
        const int o = nt * 16 + (wl_ & 15);
        const float* __restrict__ W = (o < HID) ? Wz : Wh;   // wave-uniform
        const int col = o & 31;
        ushortx8 v;
        #pragma unroll
        for (int j = 0; j < 8; ++j) {
            const int a = (kbase + j) * HID + col;
            v[j] = f2u(W[a] + W[5120 + a]);
        }
        *(ushortx8*)&sWf[e8 * 8] = v;
    }
    __syncthreads();   // the ONLY barrier

    // ---- (c) MFMA: 4 K-steps x 4 N-tiles, B streamed from LDS (conflict-free b128) ----
    floatx4 acc[4] = {{0,0,0,0},{0,0,0,0},{0,0,0,0},{0,0,0,0}};

    #pragma unroll
    for (int s = 0; s < 4; ++s) {
        ushortx8 av;
        av[0] = f2u(xa[s].x); av[1] = f2u(xa[s].y); av[2] = f2u(xa[s].z); av[3] = f2u(xa[s].w);
        av[4] = f2u(xb[s].x); av[5] = f2u(xb[s].y); av[6] = f2u(xb[s].z); av[7] = f2u(xb[s].w);
        bf16x8 afrag = __builtin_bit_cast(bf16x8, av);
        #pragma unroll
        for (int nt = 0; nt < 4; ++nt) {
            bf16x8 bfrag = __builtin_bit_cast(bf16x8,
                *(const ushortx8*)&sWf[((s * 4 + nt) * 64 + l) * 8]);
            acc[nt] = __builtin_amdgcn_mfma_f32_16x16x32_bf16(afrag, bfrag, acc[nt], 0, 0, 0);
        }
    }

    // ---- (d) epilogue: gates + relu + W_lin dot (16-lane reduce), float4 store ----
    const float bz0 = bz[n0], bz1 = bz[n0 + 16];
    const float bh0 = bh[n0], bh1 = bh[n0 + 16];
    const float wl0 = wl[n0], wl1 = wl[n0 + 16];
    const float blv = bl[0];

    float4 res;
    float* resp = &res.x;
    #pragma unroll
    for (int r = 0; r < 4; ++r) {
        float z0 = fsig(acc[0][r] + bz0);
        float z1 = fsig(acc[1][r] + bz1);
        float h0 = ftanh(acc[2][r] + bh0);
        float h1 = ftanh(acc[3][r] + bh1);
        float v0 = (1.f - z0) * h0; v0 = v0 > 0.f ? v0 : 0.f;
        float v1 = (1.f - z1) * h1; v1 = v1 > 0.f ? v1 : 0.f;
        float s = v0 * wl0 + v1 * wl1;
        s += __shfl_xor(s, 1);
        s += __shfl_xor(s, 2);
        s += __shfl_xor(s, 4);
        s += __shfl_xor(s, 8);
        resp[r] = s + blv;
    }
    if (active && n0 == 0) {
        long long m = (long long)strip * 16 + g * 4;   // m%4==0
        *(float4*)&out[m] = res;
    }
}

extern "C" void kernel_launch(void* const* d_in, const int* in_sizes, int n_in,
                              void* d_out, int out_size, void* d_ws, size_t ws_size,
                              hipStream_t stream) {
    // inputs: 0:x 1:edge_index(dead) 2:edge_weight(dead) 3:W_z 4:b_z 5:W_r(dead)
    //         6:b_r(dead) 7:W_h 8:b_h 9:W_lin 10:b_lin
    const float* x    = (const float*)d_in[0];
    const float* Wz   = (const float*)d_in[3];
    const float* bz   = (const float*)d_in[4];
    const float* Wh   = (const float*)d_in[7];
    const float* bh   = (const float*)d_in[8];
    const float* Wlin = (const float*)d_in[9];
    const float* blin = (const float*)d_in[10];
    float* out = (float*)d_out;

    const int n_nodes = in_sizes[0] / FEAT;
    const int nstrips = (n_nodes + 15) / 16;          // 6250
    const int grid = (nstrips + 3) / 4;               // 1563
    dcrnn_wave<<<grid, BLOCK, 0, stream>>>(x, Wz, Wh, bz, bh, Wlin, blin, out, n_nodes);
}

// Round 9
// 17.565 us; speedup vs baseline: 1.2930x; 1.0725x over previous
//
#include <hip/hip_runtime.h>

#define FEAT 128
#define HID 32
#define BLOCK 512        // 8 waves; ONE 16-row strip per wave
#define WPB 8

typedef __attribute__((ext_vector_type(8))) __bf16 bf16x8;
typedef __attribute__((ext_vector_type(8))) unsigned short ushortx8;
typedef __attribute__((ext_vector_type(4))) float floatx4;

static __device__ inline unsigned short f2u(float f) {
    return __builtin_bit_cast(unsigned short, (__bf16)f);   // RTNE, pairs fuse to v_cvt_pk_bf16_f32
}
static __device__ inline float fsig(float v) {
    return __builtin_amdgcn_rcpf(1.f + __expf(-v));
}
static __device__ inline float ftanh(float v) {
    return 1.f - 2.f * __builtin_amdgcn_rcpf(__expf(2.f * v) + 1.f);
}

// 8-wave autonomous: one 16-row strip per wave; W combined + staged ONCE per
// 8-wave block (halves aggregate W redundancy vs 4-wave blocks) into LDS in
// fragment-linear order; after the single barrier each wave streams its strip
// independently (direct-global A fragments, conflict-free b128 B reads).
__global__ __launch_bounds__(BLOCK) void dcrnn_wave8(
    const float* __restrict__ x,
    const float* __restrict__ Wz, const float* __restrict__ Wh,
    const float* __restrict__ bz, const float* __restrict__ bh,
    const float* __restrict__ wl, const float* __restrict__ bl,
    float* __restrict__ out, int n_nodes)
{
    __shared__ unsigned short sWf[16 * 64 * 8];   // 16 KB, fragment-linear

    const int tid = threadIdx.x;
    const int wid = tid >> 6;    // 0..7
    const int l   = tid & 63;
    const int n0  = l & 15;      // A row within strip / B col / C col
    const int g   = l >> 4;      // k-group / C row-group

    const int nstrips = (n_nodes + 15) >> 4;
    const int strip = blockIdx.x * WPB + wid;
    const bool active = strip < nstrips;

    // ---- (a) issue this wave's A loads immediately (HBM latency starts now) ----
    const long long row = (long long)(active ? strip : 0) * 16 + n0;
    const float* xr = x + row * FEAT + g * 8;
    float4 xa[4], xb[4];
    #pragma unroll
    for (int s = 0; s < 4; ++s) {
        xa[s] = *(const float4*)(xr + s * 32);
        xb[s] = *(const float4*)(xr + s * 32 + 4);
    }

    // ---- (b) cooperative W combine + stage, once per 8-wave block ----
    // W shape (2,1,160,32): [d,0,k,col] at d*5120 + k*32 + col; k<128 is the x-part.
    // sWf[((s*4+nt)*64 + lane)*8 + j] == Wc[k = s*32+(lane>>4)*8+j][o = nt*16+(lane&15)]
    #pragma unroll
    for (int p = 0; p < 2; ++p) {
        const int e8 = p * BLOCK + tid;           // ushortx8 index, 0..1023
        const int f = e8 >> 6, wl_ = e8 & 63;
        const int nt = f & 3, s = f >> 2;
        const int kbase = s * 32 + (wl_ >> 4) * 8;
        const int o = nt * 16 + (wl_ & 15);
        const float* __restrict__ W = (o < HID) ? Wz : Wh;   // wave-uniform
        const int col = o & 31;
        ushortx8 v;
        #pragma unroll
        for (int j = 0; j < 8; ++j) {
            const int a = (kbase + j) * HID + col;
            v[j] = f2u(W[a] + W[5120 + a]);
        }
        *(ushortx8*)&sWf[e8 * 8] = v;
    }
    __syncthreads();   // the ONLY barrier

    // ---- (c) MFMA: 4 K-steps x 4 N-tiles, B streamed from LDS (conflict-free b128) ----
    floatx4 acc[4] = {{0,0,0,0},{0,0,0,0},{0,0,0,0},{0,0,0,0}};

    #pragma unroll
    for (int s = 0; s < 4; ++s) {
        ushortx8 av;
        av[0] = f2u(xa[s].x); av[1] = f2u(xa[s].y); av[2] = f2u(xa[s].z); av[3] = f2u(xa[s].w);
        av[4] = f2u(xb[s].x); av[5] = f2u(xb[s].y); av[6] = f2u(xb[s].z); av[7] = f2u(xb[s].w);
        bf16x8 afrag = __builtin_bit_cast(bf16x8, av);
        #pragma unroll
        for (int nt = 0; nt < 4; ++nt) {
            bf16x8 bfrag = __builtin_bit_cast(bf16x8,
                *(const ushortx8*)&sWf[((s * 4 + nt) * 64 + l) * 8]);
            acc[nt] = __builtin_amdgcn_mfma_f32_16x16x32_bf16(afrag, bfrag, acc[nt], 0, 0, 0);
        }
    }

    // ---- (d) epilogue: gates + relu + W_lin dot (16-lane reduce), float4 store ----
    const float bz0 = bz[n0], bz1 = bz[n0 + 16];
    const float bh0 = bh[n0], bh1 = bh[n0 + 16];
    const float wl0 = wl[n0], wl1 = wl[n0 + 16];
    const float blv = bl[0];

    float4 res;
    float* resp = &res.x;
    #pragma unroll
    for (int r = 0; r < 4; ++r) {
        float z0 = fsig(acc[0][r] + bz0);
        float z1 = fsig(acc[1][r] + bz1);
        float h0 = ftanh(acc[2][r] + bh0);
        float h1 = ftanh(acc[3][r] + bh1);
        float v0 = (1.f - z0) * h0; v0 = v0 > 0.f ? v0 : 0.f;
        float v1 = (1.f - z1) * h1; v1 = v1 > 0.f ? v1 : 0.f;
        float s = v0 * wl0 + v1 * wl1;
        s += __shfl_xor(s, 1);
        s += __shfl_xor(s, 2);
        s += __shfl_xor(s, 4);
        s += __shfl_xor(s, 8);
        resp[r] = s + blv;
    }
    if (active && n0 == 0) {
        long long m = (long long)strip * 16 + g * 4;   // m%4==0
        *(float4*)&out[m] = res;
    }
}

extern "C" void kernel_launch(void* const* d_in, const int* in_sizes, int n_in,
                              void* d_out, int out_size, void* d_ws, size_t ws_size,
                              hipStream_t stream) {
    // inputs: 0:x 1:edge_index(dead) 2:edge_weight(dead) 3:W_z 4:b_z 5:W_r(dead)
    //         6:b_r(dead) 7:W_h 8:b_h 9:W_lin 10:b_lin
    const float* x    = (const float*)d_in[0];
    const float* Wz   = (const float*)d_in[3];
    const float* bz   = (const float*)d_in[4];
    const float* Wh   = (const float*)d_in[7];
    const float* bh   = (const float*)d_in[8];
    const float* Wlin = (const float*)d_in[9];
    const float* blin = (const float*)d_in[10];
    float* out = (float*)d_out;

    const int n_nodes = in_sizes[0] / FEAT;
    const int nstrips = (n_nodes + 15) / 16;          // 6250
    const int grid = (nstrips + WPB - 1) / WPB;       // 782
    dcrnn_wave8<<<grid, BLOCK, 0, stream>>>(x, Wz, Wh, bz, bh, Wlin, blin, out, n_nodes);
}

// Round 10
// 16.867 us; speedup vs baseline: 1.3465x; 1.0414x over previous
//
#include <hip/hip_runtime.h>

#define FEAT 128
#define HID 32
#define BLOCK 512        // 8 waves; TWO 16-row strips per wave
#define SPB 16           // strips per block

typedef __attribute__((ext_vector_type(8))) __bf16 bf16x8;
typedef __attribute__((ext_vector_type(8))) unsigned short ushortx8;
typedef __attribute__((ext_vector_type(4))) float floatx4;

static __device__ inline unsigned short f2u(float f) {
    return __builtin_bit_cast(unsigned short, (__bf16)f);   // RTNE, pairs fuse to v_cvt_pk_bf16_f32
}
static __device__ inline float fsig(float v) {
    return __builtin_amdgcn_rcpf(1.f + __expf(-v));
}
static __device__ inline float ftanh(float v) {
    return 1.f - 2.f * __builtin_amdgcn_rcpf(__expf(2.f * v) + 1.f);
}

// 8 waves x 2 strips/wave: W combined + staged ONCE per 16 strips (391 blocks,
// halves the dominant scalar W-staging VMEM-issue traffic vs R8). Staggered
// schedule keeps A-register pressure low: s1 loads -> W stage -> s1->bf16
// (frees fp32 regs) -> s2 loads -> barrier -> compute s1 -> compute s2.
__global__ __launch_bounds__(BLOCK, 4) void dcrnn_w2(
    const float* __restrict__ x,
    const float* __restrict__ Wz, const float* __restrict__ Wh,
    const float* __restrict__ bz, const float* __restrict__ bh,
    const float* __restrict__ wl, const float* __restrict__ bl,
    float* __restrict__ out, int n_nodes)
{
    __shared__ unsigned short sWf[16 * 64 * 8];   // 16 KB, fragment-linear

    const int tid = threadIdx.x;
    const int wid = tid >> 6;    // 0..7
    const int l   = tid & 63;
    const int n0  = l & 15;      // A row within strip / B col / C col
    const int g   = l >> 4;      // k-group / C row-group

    const int nstrips = (n_nodes + 15) >> 4;      // 6250
    const int base = blockIdx.x * SPB;
    const int s1 = base + wid;
    const int s2 = base + wid + 8;
    const bool act1 = s1 < nstrips;
    const bool act2 = s2 < nstrips;

    // ---- (a) issue strip-1 A loads (HBM latency starts now) ----
    const long long row1 = (long long)(act1 ? s1 : 0) * 16 + n0;
    const float* xr1 = x + row1 * FEAT + g * 8;
    float4 xa1[4], xb1[4];
    #pragma unroll
    for (int s = 0; s < 4; ++s) {
        xa1[s] = *(const float4*)(xr1 + s * 32);
        xb1[s] = *(const float4*)(xr1 + s * 32 + 4);
    }

    // ---- (b) cooperative W combine + stage, once per 16 strips ----
    // W shape (2,1,160,32): [d,0,k,col] at d*5120 + k*32 + col; k<128 is the x-part.
    // sWf[((s*4+nt)*64 + lane)*8 + j] == Wc[k = s*32+(lane>>4)*8+j][o = nt*16+(lane&15)]
    #pragma unroll
    for (int p = 0; p < 2; ++p) {
        const int e8 = p * BLOCK + tid;           // ushortx8 index, 0..1023
        const int f = e8 >> 6, wl_ = e8 & 63;
        const int nt = f & 3, sk = f >> 2;
        const int kbase = sk * 32 + (wl_ >> 4) * 8;
        const int o = nt * 16 + (wl_ & 15);
        const float* __restrict__ W = (o < HID) ? Wz : Wh;   // wave-uniform
        const int col = o & 31;
        ushortx8 v;
        #pragma unroll
        for (int j = 0; j < 8; ++j) {
            const int a = (kbase + j) * HID + col;
            v[j] = f2u(W[a] + W[5120 + a]);
        }
        *(ushortx8*)&sWf[e8 * 8] = v;
    }

    // ---- (c) epilogue constants (once per wave) ----
    const float bz0 = bz[n0], bz1 = bz[n0 + 16];
    const float bh0 = bh[n0], bh1 = bh[n0 + 16];
    const float wl0 = wl[n0], wl1 = wl[n0 + 16];
    const float blv = bl[0];

    // ---- (d) strip-1 fp32 -> bf16 frags (frees the fp32 regs) ----
    bf16x8 af1[4];
    #pragma unroll
    for (int s = 0; s < 4; ++s) {
        ushortx8 av;
        av[0] = f2u(xa1[s].x); av[1] = f2u(xa1[s].y); av[2] = f2u(xa1[s].z); av[3] = f2u(xa1[s].w);
        av[4] = f2u(xb1[s].x); av[5] = f2u(xb1[s].y); av[6] = f2u(xb1[s].z); av[7] = f2u(xb1[s].w);
        af1[s] = __builtin_bit_cast(bf16x8, av);
    }

    // ---- (e) issue strip-2 A loads (hide under strip-1 compute + TLP) ----
    const long long row2 = (long long)(act2 ? s2 : 0) * 16 + n0;
    const float* xr2 = x + row2 * FEAT + g * 8;
    float4 xa2[4], xb2[4];
    #pragma unroll
    for (int s = 0; s < 4; ++s) {
        xa2[s] = *(const float4*)(xr2 + s * 32);
        xb2[s] = *(const float4*)(xr2 + s * 32 + 4);
    }

    __syncthreads();   // the ONLY barrier

    // ---- (f) strip-1: MFMA + epilogue ----
    {
        floatx4 acc[4] = {{0,0,0,0},{0,0,0,0},{0,0,0,0},{0,0,0,0}};
        #pragma unroll
        for (int s = 0; s < 4; ++s) {
            #pragma unroll
            for (int nt = 0; nt < 4; ++nt) {
                bf16x8 bfrag = __builtin_bit_cast(bf16x8,
                    *(const ushortx8*)&sWf[((s * 4 + nt) * 64 + l) * 8]);
                acc[nt] = __builtin_amdgcn_mfma_f32_16x16x32_bf16(af1[s], bfrag, acc[nt], 0, 0, 0);
            }
        }
        float4 res; float* resp = &res.x;
        #pragma unroll
        for (int r = 0; r < 4; ++r) {
            float z0 = fsig(acc[0][r] + bz0);
            float z1 = fsig(acc[1][r] + bz1);
            float h0 = ftanh(acc[2][r] + bh0);
            float h1 = ftanh(acc[3][r] + bh1);
            float v0 = (1.f - z0) * h0; v0 = v0 > 0.f ? v0 : 0.f;
            float v1 = (1.f - z1) * h1; v1 = v1 > 0.f ? v1 : 0.f;
            float sm = v0 * wl0 + v1 * wl1;
            sm += __shfl_xor(sm, 1);
            sm += __shfl_xor(sm, 2);
            sm += __shfl_xor(sm, 4);
            sm += __shfl_xor(sm, 8);
            resp[r] = sm + blv;
        }
        if (act1 && n0 == 0) {
            long long m = (long long)s1 * 16 + g * 4;   // m%4==0
            *(float4*)&out[m] = res;
        }
    }

    // ---- (g) strip-2: convert + MFMA + epilogue ----
    {
        floatx4 acc[4] = {{0,0,0,0},{0,0,0,0},{0,0,0,0},{0,0,0,0}};
        #pragma unroll
        for (int s = 0; s < 4; ++s) {
            ushortx8 av;
            av[0] = f2u(xa2[s].x); av[1] = f2u(xa2[s].y); av[2] = f2u(xa2[s].z); av[3] = f2u(xa2[s].w);
            av[4] = f2u(xb2[s].x); av[5] = f2u(xb2[s].y); av[6] = f2u(xb2[s].z); av[7] = f2u(xb2[s].w);
            bf16x8 afrag = __builtin_bit_cast(bf16x8, av);
            #pragma unroll
            for (int nt = 0; nt < 4; ++nt) {
                bf16x8 bfrag = __builtin_bit_cast(bf16x8,
                    *(const ushortx8*)&sWf[((s * 4 + nt) * 64 + l) * 8]);
                acc[nt] = __builtin_amdgcn_mfma_f32_16x16x32_bf16(afrag, bfrag, acc[nt], 0, 0, 0);
            }
        }
        float4 res; float* resp = &res.x;
        #pragma unroll
        for (int r = 0; r < 4; ++r) {
            float z0 = fsig(acc[0][r] + bz0);
            float z1 = fsig(acc[1][r] + bz1);
            float h0 = ftanh(acc[2][r] + bh0);
            float h1 = ftanh(acc[3][r] + bh1);
            float v0 = (1.f - z0) * h0; v0 = v0 > 0.f ? v0 : 0.f;
            float v1 = (1.f - z1) * h1; v1 = v1 > 0.f ? v1 : 0.f;
            float sm = v0 * wl0 + v1 * wl1;
            sm += __shfl_xor(sm, 1);
            sm += __shfl_xor(sm, 2);
            sm += __shfl_xor(sm, 4);
            sm += __shfl_xor(sm, 8);
            resp[r] = sm + blv;
        }
        if (act2 && n0 == 0) {
            long long m = (long long)s2 * 16 + g * 4;   // m%4==0
            *(float4*)&out[m] = res;
        }
    }
}

extern "C" void kernel_launch(void* const* d_in, const int* in_sizes, int n_in,
                              void* d_out, int out_size, void* d_ws, size_t ws_size,
                              hipStream_t stream) {
    // inputs: 0:x 1:edge_index(dead) 2:edge_weight(dead) 3:W_z 4:b_z 5:W_r(dead)
    //         6:b_r(dead) 7:W_h 8:b_h 9:W_lin 10:b_lin
    const float* x    = (const float*)d_in[0];
    const float* Wz   = (const float*)d_in[3];
    const float* bz   = (const float*)d_in[4];
    const float* Wh   = (const float*)d_in[7];
    const float* bh   = (const float*)d_in[8];
    const float* Wlin = (const float*)d_in[9];
    const float* blin = (const float*)d_in[10];
    float* out = (float*)d_out;

    const int n_nodes = in_sizes[0] / FEAT;
    const int nstrips = (n_nodes + 15) / 16;          // 6250
    const int grid = (nstrips + SPB - 1) / SPB;       // 391
    dcrnn_w2<<<grid, BLOCK, 0, stream>>>(x, Wz, Wh, bz, bh, Wlin, blin, out, n_nodes);
}